// Round 2
// baseline (1157.371 us; speedup 1.0000x reference)
//
#include <hip/hip_runtime.h>
#include <hip/hip_bf16.h>
#include <math.h>

// LGNGuard: 3-layer guarded LightGCN propagation + sigmoid(U @ I^T) scoring.
// D=64 fixed (lane==dim for wave-per-edge/node kernels).

#define DD 64

// ---- per-node L2 norms: wave per node, lane = dim ----
__global__ __launch_bounds__(256) void node_norms_k(const float* __restrict__ emb,
                                                    float* __restrict__ norms, int n) {
    int lane = threadIdx.x & 63;
    int wid  = (blockIdx.x * blockDim.x + threadIdx.x) >> 6;
    int nw   = (gridDim.x * blockDim.x) >> 6;
    for (int node = wid; node < n; node += nw) {
        float v = emb[(size_t)node * DD + lane];
        float s = v * v;
#pragma unroll
        for (int m = 32; m > 0; m >>= 1) s += __shfl_xor(s, m, 64);
        if (lane == 0) norms[node] = sqrtf(s);
    }
}

// ---- per-edge cosine + rowsum(|cos|) accumulation: wave per edge ----
__global__ __launch_bounds__(256) void edge_cos_k(const float* __restrict__ emb,
                                                  const float* __restrict__ norms,
                                                  const int* __restrict__ src,
                                                  const int* __restrict__ dst,
                                                  float* __restrict__ cosbuf,
                                                  float* __restrict__ rowsum, int E) {
    int lane = threadIdx.x & 63;
    int wid  = (blockIdx.x * blockDim.x + threadIdx.x) >> 6;
    int nw   = (gridDim.x * blockDim.x) >> 6;
    for (int e = wid; e < E; e += nw) {
        int s = src[e], t = dst[e];
        float a = emb[(size_t)s * DD + lane];
        float b = emb[(size_t)t * DD + lane];
        float p = a * b;
#pragma unroll
        for (int m = 32; m > 0; m >>= 1) p += __shfl_xor(p, m, 64);
        if (lane == 0) {
            float den = fmaxf(norms[s] * norms[t], 1e-8f);
            float c = p / den;
            cosbuf[e] = c;
            atomicAdd(&rowsum[s], fabsf(c));
        }
    }
}

// ---- normalize (on the fly) + prune (sigmoid(z)>0.5 <=> z>0) + memory EMA ----
// coef[e]      = cos[e]      / guard(rowsum[src[e]])
// coef[rev[e]] = cos[rev[e]] / guard(rowsum[src[rev[e]]]) ; src[rev[e]] == dst[e]
__global__ __launch_bounds__(256) void prune_mem_k(const float* __restrict__ cosbuf,
                                                   const float* __restrict__ rowsum,
                                                   const int* __restrict__ src,
                                                   const int* __restrict__ dst,
                                                   const int* __restrict__ rev,
                                                   const float* __restrict__ Wp,
                                                   const float* __restrict__ bp,
                                                   float* __restrict__ mem, int E) {
    int e = blockIdx.x * blockDim.x + threadIdx.x;
    if (e >= E) return;
    float rs = rowsum[src[e]];
    float rd = rowsum[dst[e]];
    float c  = cosbuf[e]      / (rs > 0.f ? rs : 1.f);
    float cr = cosbuf[rev[e]] / (rd > 0.f ? rd : 1.f);
    float z  = Wp[0] * c + Wp[1] * cr + bp[0];
    float kept = (z > 0.f) ? c : 0.f;
    mem[e] = 0.5f * mem[e] + 0.5f * kept;
}

// ---- SpMM scatter: wave per edge, atomicAdd into out rows ----
__global__ __launch_bounds__(256) void spmm_k(const float* __restrict__ emb,
                                              const int* __restrict__ src,
                                              const int* __restrict__ dst,
                                              const float* __restrict__ mem,
                                              const float* __restrict__ adj,
                                              float* __restrict__ out, int E) {
    int lane = threadIdx.x & 63;
    int wid  = (blockIdx.x * blockDim.x + threadIdx.x) >> 6;
    int nw   = (gridDim.x * blockDim.x) >> 6;
    for (int e = wid; e < E; e += nw) {
        int s = src[e], t = dst[e];
        float g = mem[e] * adj[e];
        atomicAdd(&out[(size_t)s * DD + lane], g * emb[(size_t)t * DD + lane]);
    }
}

// ---- accumulate selected (user/item) rows of the running embedding sum ----
__global__ __launch_bounds__(256) void acc_update_k(const float* __restrict__ emb,
                                                    const int* __restrict__ users,
                                                    const int* __restrict__ items,
                                                    float* __restrict__ acc,
                                                    int BU, int BI, int NU, int init) {
    int tid = blockIdx.x * blockDim.x + threadIdx.x;
    int total = (BU + BI) * DD;
    if (tid >= total) return;
    int row = tid >> 6, d = tid & 63;
    int node = (row < BU) ? users[row] : (NU + items[row - BU]);
    float v = emb[(size_t)node * DD + d];
    if (init) acc[tid] = v;
    else      acc[tid] += v;
}

// ---- final: sigmoid( (accU/4) . (accI/4) ) = sigmoid(dot/16) ----
__global__ __launch_bounds__(256) void final_gemm_k(const float* __restrict__ acc,
                                                    float* __restrict__ out,
                                                    int BU, int BI) {
    __shared__ float Us[16][64];
    __shared__ float Is[16][65];
    int tx = threadIdx.x & 15, ty = threadIdx.x >> 4;
    int i0 = blockIdx.y * 16, j0 = blockIdx.x * 16;
    for (int t = threadIdx.x; t < 16 * 64; t += 256) {
        int r = t >> 6, k = t & 63;
        Us[r][k] = acc[(size_t)(i0 + r) * DD + k];
        Is[r][k] = acc[(size_t)(BU + j0 + r) * DD + k];
    }
    __syncthreads();
    float sum = 0.f;
#pragma unroll
    for (int k = 0; k < 64; ++k) sum += Us[ty][k] * Is[tx][k];
    float z = sum * 0.0625f;
    out[(size_t)(i0 + ty) * BI + (j0 + tx)] = 1.f / (1.f + expf(-z));
}

extern "C" void kernel_launch(void* const* d_in, const int* in_sizes, int n_in,
                              void* d_out, int out_size, void* d_ws, size_t ws_size,
                              hipStream_t stream) {
    const int*   users    = (const int*)d_in[0];
    const int*   items    = (const int*)d_in[1];
    const float* user_emb = (const float*)d_in[2];
    const float* item_emb = (const float*)d_in[3];
    const float* Wp       = (const float*)d_in[4];
    const float* bp       = (const float*)d_in[5];
    const int*   src      = (const int*)d_in[6];
    const int*   dst      = (const int*)d_in[7];
    const int*   rev      = (const int*)d_in[8];
    const float* adj      = (const float*)d_in[9];

    int BU = in_sizes[0];
    int BI = in_sizes[1];
    int NU = in_sizes[2] / DD;
    int NI = in_sizes[3] / DD;
    int Nn = NU + NI;
    int E  = in_sizes[6];

    float* ws     = (float*)d_ws;
    float* embA   = ws;
    float* embB   = embA + (size_t)Nn * DD;
    float* norms  = embB + (size_t)Nn * DD;
    float* rowsum = norms + Nn;
    float* coef   = rowsum + Nn;
    float* mem    = coef + E;
    float* acc    = mem + E;

    // emb0 = concat(user_emb, item_emb); mem0 = adj_vals
    hipMemcpyAsync(embA, user_emb, sizeof(float) * (size_t)NU * DD,
                   hipMemcpyDeviceToDevice, stream);
    hipMemcpyAsync(embA + (size_t)NU * DD, item_emb, sizeof(float) * (size_t)NI * DD,
                   hipMemcpyDeviceToDevice, stream);
    hipMemcpyAsync(mem, adj, sizeof(float) * (size_t)E, hipMemcpyDeviceToDevice, stream);

    int accThreads = (BU + BI) * DD;
    acc_update_k<<<(accThreads + 255) / 256, 256, 0, stream>>>(embA, users, items, acc,
                                                               BU, BI, NU, 1);

    float* cur = embA;
    float* nxt = embB;
    for (int layer = 0; layer < 3; ++layer) {
        hipMemsetAsync(rowsum, 0, sizeof(float) * (size_t)Nn, stream);
        hipMemsetAsync(nxt, 0, sizeof(float) * (size_t)Nn * DD, stream);
        node_norms_k<<<1024, 256, 0, stream>>>(cur, norms, Nn);
        edge_cos_k<<<2048, 256, 0, stream>>>(cur, norms, src, dst, coef, rowsum, E);
        prune_mem_k<<<(E + 255) / 256, 256, 0, stream>>>(coef, rowsum, src, dst, rev,
                                                         Wp, bp, mem, E);
        spmm_k<<<2048, 256, 0, stream>>>(cur, src, dst, mem, adj, nxt, E);
        acc_update_k<<<(accThreads + 255) / 256, 256, 0, stream>>>(nxt, users, items, acc,
                                                                   BU, BI, NU, 0);
        float* t = cur; cur = nxt; nxt = t;
    }

    dim3 grid(BI / 16, BU / 16);
    final_gemm_k<<<grid, 256, 0, stream>>>(acc, (float*)d_out, BU, BI);
}

// Round 3
// 582.942 us; speedup vs baseline: 1.9854x; 1.9854x over previous
//
#include <hip/hip_runtime.h>
#include <hip/hip_bf16.h>
#include <math.h>

// LGNGuard: 3-layer guarded LightGCN propagation + sigmoid(U @ I^T) scoring.
// CSR-based: edges grouped by src row -> no atomics in the hot passes.
// D=64 fixed. Quad layout: 4 lanes per edge/row, 16 dims per lane (4x float4).

#define DD 64

// ================= CSR build =================

__global__ __launch_bounds__(256) void hist_k(const int* __restrict__ src,
                                              int* __restrict__ deg, int E) {
    int e = blockIdx.x * blockDim.x + threadIdx.x;
    if (e < E) atomicAdd(&deg[src[e]], 1);
}

// exclusive scan, 1024 elements per block
__global__ __launch_bounds__(256) void scan1_k(const int* __restrict__ in,
                                               int* __restrict__ out,
                                               int* __restrict__ partial, int M) {
    __shared__ int sh[256];
    int base = blockIdx.x * 1024;
    int t = threadIdx.x;
    int i0 = base + t * 4;
    int v0 = (i0 + 0 < M) ? in[i0 + 0] : 0;
    int v1 = (i0 + 1 < M) ? in[i0 + 1] : 0;
    int v2 = (i0 + 2 < M) ? in[i0 + 2] : 0;
    int v3 = (i0 + 3 < M) ? in[i0 + 3] : 0;
    int tsum = v0 + v1 + v2 + v3;
    sh[t] = tsum;
    __syncthreads();
    for (int off = 1; off < 256; off <<= 1) {
        int x = (t >= off) ? sh[t - off] : 0;
        __syncthreads();
        sh[t] += x;
        __syncthreads();
    }
    int texcl = sh[t] - tsum;
    if (i0 + 0 < M) out[i0 + 0] = texcl;
    if (i0 + 1 < M) out[i0 + 1] = texcl + v0;
    if (i0 + 2 < M) out[i0 + 2] = texcl + v0 + v1;
    if (i0 + 3 < M) out[i0 + 3] = texcl + v0 + v1 + v2;
    if (t == 255) partial[blockIdx.x] = sh[255];
}

__global__ __launch_bounds__(256) void scan2_k(int* __restrict__ partial, int nc) {
    __shared__ int sh[256];
    int t = threadIdx.x;
    int v = (t < nc) ? partial[t] : 0;
    sh[t] = v;
    __syncthreads();
    for (int off = 1; off < 256; off <<= 1) {
        int x = (t >= off) ? sh[t - off] : 0;
        __syncthreads();
        sh[t] += x;
        __syncthreads();
    }
    if (t < nc) partial[t] = sh[t] - v;
}

__global__ __launch_bounds__(256) void scan3_k(int* __restrict__ out,
                                               const int* __restrict__ partial, int M) {
    int i = blockIdx.x * blockDim.x + threadIdx.x;
    if (i < M) out[i] += partial[i >> 10];
}

// scatter edges into CSR slots; also pull per-edge values into CSR order
__global__ __launch_bounds__(256) void scatter_k(const int* __restrict__ src,
                                                 const int* __restrict__ dst,
                                                 const float* __restrict__ adj,
                                                 int* __restrict__ cursor,
                                                 int* __restrict__ dsts,
                                                 int* __restrict__ srcs,
                                                 float* __restrict__ adjc,
                                                 float* __restrict__ memc,
                                                 int* __restrict__ csrpos, int E) {
    int e = blockIdx.x * blockDim.x + threadIdx.x;
    if (e >= E) return;
    int r = src[e];
    int pos = atomicAdd(&cursor[r], 1);
    dsts[pos] = dst[e];
    srcs[pos] = r;
    float a = adj[e];
    adjc[pos] = a;
    memc[pos] = a;
    csrpos[e] = pos;
}

__global__ __launch_bounds__(256) void revpos_k(const int* __restrict__ csrpos,
                                                const int* __restrict__ rev,
                                                int* __restrict__ revpos, int E) {
    int e = blockIdx.x * blockDim.x + threadIdx.x;
    if (e >= E) return;
    revpos[csrpos[e]] = csrpos[rev[e]];
}

// ================= per-layer =================

__global__ __launch_bounds__(256) void node_norms_k(const float* __restrict__ emb,
                                                    float* __restrict__ norms, int n) {
    int lane = threadIdx.x & 63;
    int wid  = (blockIdx.x * blockDim.x + threadIdx.x) >> 6;
    int nw   = (gridDim.x * blockDim.x) >> 6;
    for (int node = wid; node < n; node += nw) {
        float v = emb[(size_t)node * DD + lane];
        float s = v * v;
#pragma unroll
        for (int m = 32; m > 0; m >>= 1) s += __shfl_xor(s, m, 64);
        if (lane == 0) norms[node] = sqrtf(s);
    }
}

// cos + rowsum, quad per row. emb row held in regs; rowsum in reg (no atomics).
__global__ __launch_bounds__(256) void cos_row_k(const float* __restrict__ emb,
                                                 const float* __restrict__ norms,
                                                 const int* __restrict__ rp,
                                                 const int* __restrict__ dsts,
                                                 float* __restrict__ cosc,
                                                 float* __restrict__ rowsum, int N) {
    int quad = (blockIdx.x * blockDim.x + threadIdx.x) >> 2;
    int l4   = threadIdx.x & 3;
    if (quad >= N) return;
    int r  = quad;
    int p0 = rp[r], p1 = rp[r + 1];
    const float4* embv = (const float4*)emb;
    float4 A[4];
#pragma unroll
    for (int k = 0; k < 4; ++k) A[k] = embv[(size_t)r * 16 + k * 4 + l4];
    float nr = norms[r];
    float rs = 0.f;
    for (int p = p0; p < p1; ++p) {
        int d = dsts[p];
        float dot = 0.f;
#pragma unroll
        for (int k = 0; k < 4; ++k) {
            float4 b = embv[(size_t)d * 16 + k * 4 + l4];
            dot += A[k].x * b.x + A[k].y * b.y + A[k].z * b.z + A[k].w * b.w;
        }
        dot += __shfl_xor(dot, 1, 64);
        dot += __shfl_xor(dot, 2, 64);
        float c = dot / fmaxf(nr * norms[d], 1e-8f);
        if (l4 == 0) cosc[p] = c;
        rs += fabsf(c);
    }
    if (l4 == 0) rowsum[r] = rs;
}

// normalize + prune (sigmoid(z)>0.5 <=> z>0) + memory EMA, all in CSR space
__global__ __launch_bounds__(256) void prune_mem_k(const float* __restrict__ cosc,
                                                   const float* __restrict__ rowsum,
                                                   const int* __restrict__ srcs,
                                                   const int* __restrict__ dsts,
                                                   const int* __restrict__ revpos,
                                                   const float* __restrict__ Wp,
                                                   const float* __restrict__ bp,
                                                   float* __restrict__ memc, int E) {
    int p = blockIdx.x * blockDim.x + threadIdx.x;
    if (p >= E) return;
    float rs = rowsum[srcs[p]];
    float rd = rowsum[dsts[p]];
    float c  = cosc[p]         / (rs > 0.f ? rs : 1.f);
    float cr = cosc[revpos[p]] / (rd > 0.f ? rd : 1.f);
    float z  = Wp[0] * c + Wp[1] * cr + bp[0];
    float kept = (z > 0.f) ? c : 0.f;
    memc[p] = 0.5f * memc[p] + 0.5f * kept;
}

// SpMM, quad per row: accumulate in regs, one streaming write. No atomics.
__global__ __launch_bounds__(256) void spmm_row_k(const float* __restrict__ emb,
                                                  const int* __restrict__ rp,
                                                  const int* __restrict__ dsts,
                                                  const float* __restrict__ memc,
                                                  const float* __restrict__ adjc,
                                                  float* __restrict__ out, int N) {
    int quad = (blockIdx.x * blockDim.x + threadIdx.x) >> 2;
    int l4   = threadIdx.x & 3;
    if (quad >= N) return;
    int r  = quad;
    int p0 = rp[r], p1 = rp[r + 1];
    const float4* embv = (const float4*)emb;
    float4 acc[4];
#pragma unroll
    for (int k = 0; k < 4; ++k) acc[k] = make_float4(0.f, 0.f, 0.f, 0.f);
    for (int p = p0; p < p1; ++p) {
        int d = dsts[p];
        float g = memc[p] * adjc[p];
#pragma unroll
        for (int k = 0; k < 4; ++k) {
            float4 b = embv[(size_t)d * 16 + k * 4 + l4];
            acc[k].x += g * b.x;
            acc[k].y += g * b.y;
            acc[k].z += g * b.z;
            acc[k].w += g * b.w;
        }
    }
    float4* outv = (float4*)out;
#pragma unroll
    for (int k = 0; k < 4; ++k) outv[(size_t)r * 16 + k * 4 + l4] = acc[k];
}

// ================= selected-row accumulation + scoring =================

__global__ __launch_bounds__(256) void acc_update_k(const float* __restrict__ emb,
                                                    const int* __restrict__ users,
                                                    const int* __restrict__ items,
                                                    float* __restrict__ acc,
                                                    int BU, int BI, int NU, int init) {
    int tid = blockIdx.x * blockDim.x + threadIdx.x;
    int total = (BU + BI) * DD;
    if (tid >= total) return;
    int row = tid >> 6, d = tid & 63;
    int node = (row < BU) ? users[row] : (NU + items[row - BU]);
    float v = emb[(size_t)node * DD + d];
    if (init) acc[tid] = v;
    else      acc[tid] += v;
}

__global__ __launch_bounds__(256) void final_gemm_k(const float* __restrict__ acc,
                                                    float* __restrict__ out,
                                                    int BU, int BI) {
    __shared__ float Us[16][64];
    __shared__ float Is[16][65];
    int tx = threadIdx.x & 15, ty = threadIdx.x >> 4;
    int i0 = blockIdx.y * 16, j0 = blockIdx.x * 16;
    for (int t = threadIdx.x; t < 16 * 64; t += 256) {
        int r = t >> 6, k = t & 63;
        Us[r][k] = acc[(size_t)(i0 + r) * DD + k];
        Is[r][k] = acc[(size_t)(BU + j0 + r) * DD + k];
    }
    __syncthreads();
    float sum = 0.f;
#pragma unroll
    for (int k = 0; k < 64; ++k) sum += Us[ty][k] * Is[tx][k];
    float z = sum * 0.0625f;
    out[(size_t)(i0 + ty) * BI + (j0 + tx)] = 1.f / (1.f + expf(-z));
}

// ================= launch =================

extern "C" void kernel_launch(void* const* d_in, const int* in_sizes, int n_in,
                              void* d_out, int out_size, void* d_ws, size_t ws_size,
                              hipStream_t stream) {
    const int*   users    = (const int*)d_in[0];
    const int*   items    = (const int*)d_in[1];
    const float* user_emb = (const float*)d_in[2];
    const float* item_emb = (const float*)d_in[3];
    const float* Wp       = (const float*)d_in[4];
    const float* bp       = (const float*)d_in[5];
    const int*   src      = (const int*)d_in[6];
    const int*   dst      = (const int*)d_in[7];
    const int*   rev      = (const int*)d_in[8];
    const float* adj      = (const float*)d_in[9];

    int BU = in_sizes[0];
    int BI = in_sizes[1];
    int NU = in_sizes[2] / DD;
    int NI = in_sizes[3] / DD;
    int Nn = NU + NI;
    int E  = in_sizes[6];
    int M  = Nn + 1;

    float* ws     = (float*)d_ws;
    float* embA   = ws;                              // Nn*64
    float* embB   = embA + (size_t)Nn * DD;          // Nn*64
    float* norms  = embB + (size_t)Nn * DD;          // Nn
    float* rowsum = norms + Nn;                      // Nn
    float* adjc   = rowsum + Nn;                     // E
    float* memc   = adjc + E;                        // E
    float* cosc   = memc + E;                        // E
    float* acc    = cosc + E;                        // (BU+BI)*64
    int*   deg    = (int*)(acc + (size_t)(BU + BI) * DD);  // M
    int*   rp     = deg + M;                         // M
    int*   cursor = rp + M;                          // Nn
    int*   dsts   = cursor + Nn;                     // E
    int*   srcs   = dsts + E;                        // E
    int*   revpos = srcs + E;                        // E
    int*   partial= revpos + E;                      // 256
    int*   csrpos = (int*)embB;                      // build-time only, aliases embB

    int eb = (E + 255) / 256;
    int nc = (M + 1023) / 1024;

    // ---- CSR build ----
    hipMemsetAsync(deg, 0, sizeof(int) * (size_t)M, stream);
    hist_k<<<eb, 256, 0, stream>>>(src, deg, E);
    scan1_k<<<nc, 256, 0, stream>>>(deg, rp, partial, M);
    scan2_k<<<1, 256, 0, stream>>>(partial, nc);
    scan3_k<<<(M + 255) / 256, 256, 0, stream>>>(rp, partial, M);
    hipMemcpyAsync(cursor, rp, sizeof(int) * (size_t)Nn, hipMemcpyDeviceToDevice, stream);
    scatter_k<<<eb, 256, 0, stream>>>(src, dst, adj, cursor, dsts, srcs, adjc, memc,
                                      csrpos, E);
    revpos_k<<<eb, 256, 0, stream>>>(csrpos, rev, revpos, E);

    // ---- emb0 = concat(user_emb, item_emb) ----
    hipMemcpyAsync(embA, user_emb, sizeof(float) * (size_t)NU * DD,
                   hipMemcpyDeviceToDevice, stream);
    hipMemcpyAsync(embA + (size_t)NU * DD, item_emb, sizeof(float) * (size_t)NI * DD,
                   hipMemcpyDeviceToDevice, stream);

    int accThreads = (BU + BI) * DD;
    acc_update_k<<<(accThreads + 255) / 256, 256, 0, stream>>>(embA, users, items, acc,
                                                               BU, BI, NU, 1);

    int rowBlocks = (4 * Nn + 255) / 256;
    float* cur = embA;
    float* nxt = embB;
    for (int layer = 0; layer < 3; ++layer) {
        node_norms_k<<<1024, 256, 0, stream>>>(cur, norms, Nn);
        cos_row_k<<<rowBlocks, 256, 0, stream>>>(cur, norms, rp, dsts, cosc, rowsum, Nn);
        prune_mem_k<<<eb, 256, 0, stream>>>(cosc, rowsum, srcs, dsts, revpos,
                                            Wp, bp, memc, E);
        spmm_row_k<<<rowBlocks, 256, 0, stream>>>(cur, rp, dsts, memc, adjc, nxt, Nn);
        acc_update_k<<<(accThreads + 255) / 256, 256, 0, stream>>>(nxt, users, items, acc,
                                                                   BU, BI, NU, 0);
        float* t = cur; cur = nxt; nxt = t;
    }

    dim3 grid(BI / 16, BU / 16);
    final_gemm_k<<<grid, 256, 0, stream>>>(acc, (float*)d_out, BU, BI);
}